// Round 8
// baseline (650.601 us; speedup 1.0000x reference)
//
#include <hip/hip_runtime.h>
#include <math.h>

#define N_NODES 100000
#define D_IN 256
#define H1 16
#define H2 32
#define NT1 1563                 // xw1: one 16-row MFMA tile per wave
#define BSHIFT 6                 // 64 rows per bucket
#define BROWS 64
#define NB 1563                  // ceil(N_NODES / 64)
#define CH 8192                  // edges per scatter chunk
#define GSPLIT 4                 // blocks per bucket in gacc

// ---------- bf16 helpers (manual, RNE) ----------
static __device__ __forceinline__ float bf_lo(unsigned int u) {
    return __uint_as_float(u << 16);
}
static __device__ __forceinline__ float bf_hi(unsigned int u) {
    return __uint_as_float(u & 0xffff0000u);
}
static __device__ __forceinline__ unsigned int f2bf_rne(float f) {
    unsigned int u = __float_as_uint(f);
    return (u + 0x7fffu + ((u >> 16) & 1u)) >> 16;
}
static __device__ __forceinline__ unsigned int pack_bf16(float lo, float hi) {
    return f2bf_rne(lo) | (f2bf_rne(hi) << 16);
}
static __device__ __forceinline__ unsigned int cvt_pk_bf16(float lo, float hi) {
    unsigned int r;
    asm("v_cvt_pk_bf16_f32 %0, %1, %2" : "=v"(r) : "v"(lo), "v"(hi));
    return r;
}

typedef __attribute__((ext_vector_type(8))) short bf16x8;
typedef __attribute__((ext_vector_type(4))) float f32x4;
union ABFrag { unsigned int u[4]; bf16x8 v; };

// ---------------- launch 1: t = bf16(x@W1) + fused zero of g2/s/flag/hist -
// r6-proven MFMA version (absmax 0). A: row=l&15, k=(l>>4)*8+e;
// B: col=l&15 same k; D: col=l&15, row=(l>>4)*4+reg.
__global__ __launch_bounds__(256) void k_xw1z(const float* __restrict__ x,
                                              const float* __restrict__ W1,
                                              unsigned short* __restrict__ t,
                                              float4* __restrict__ zero4) {
    const int tid = threadIdx.x;
    const int bid = blockIdx.x;

    // zero [g2 | s | flag | hist] = 200,464 float4 over 400,128 threads
    int zi = bid * 256 + tid;
    if (zi < 200464) zero4[zi] = make_float4(0.f, 0.f, 0.f, 0.f);

    const int lane = tid & 63;
    const int wid  = tid >> 6;
    const int fcol = lane & 15;
    const int kgrp = lane >> 4;

    ABFrag bfrag[8];
#pragma unroll
    for (int g = 0; g < 8; g++) {
        const float* wp = W1 + (g * 32 + kgrp * 8) * H1 + fcol;
#pragma unroll
        for (int p = 0; p < 4; p++)
            bfrag[g].u[p] = cvt_pk_bf16(wp[(2 * p) * H1], wp[(2 * p + 1) * H1]);
    }

    const int row0 = bid * 64 + wid * 16;
    int arow = row0 + fcol;
    if (arow >= N_NODES) arow = N_NODES - 1;   // clamp for safe loads
    const float* xr = x + (size_t)arow * D_IN;
    f32x4 acc = {0.f, 0.f, 0.f, 0.f};
#pragma unroll
    for (int g = 0; g < 8; g++) {
        const float4 a0 = *(const float4*)(xr + g * 32 + kgrp * 8);
        const float4 a1 = *(const float4*)(xr + g * 32 + kgrp * 8 + 4);
        ABFrag af;
        af.u[0] = cvt_pk_bf16(a0.x, a0.y);
        af.u[1] = cvt_pk_bf16(a0.z, a0.w);
        af.u[2] = cvt_pk_bf16(a1.x, a1.y);
        af.u[3] = cvt_pk_bf16(a1.z, a1.w);
        acc = __builtin_amdgcn_mfma_f32_16x16x32_bf16(af.v, bfrag[g].v, acc, 0, 0, 0);
    }
#pragma unroll
    for (int r = 0; r < 4; r++) {
        int orow = row0 + kgrp * 4 + r;
        if (orow < N_NODES)
            t[(size_t)orow * H1 + fcol] = (unsigned short)f2bf_rne(acc[r]);
    }
}

// ---------------- launch 2: bucket histogram (r3-proven structure) --------
__global__ __launch_bounds__(256) void k_hist(const int* __restrict__ rows,
                                              int* __restrict__ hist, int E) {
    __shared__ int lh[NB];
    int tid = threadIdx.x;
    for (int b = tid; b < NB; b += 256) lh[b] = 0;
    __syncthreads();
    int stride = gridDim.x * 256;
    for (int i = blockIdx.x * 256 + tid; i < E; i += stride)
        atomicAdd(&lh[rows[i] >> BSHIFT], 1);
    __syncthreads();
    for (int b = tid; b < NB; b += 256) {
        int c = lh[b];
        if (c) atomicAdd(&hist[b], c);
    }
}

// ---------------- launch 3: exclusive scan -> base, init cursors ----------
// (verbatim structure from r4 mega phase B, which produced absmax 0)
__global__ __launch_bounds__(256) void k_scan(const int* __restrict__ hist,
                                              int* __restrict__ base,
                                              unsigned int* __restrict__ cursor) {
    __shared__ int scan[256];
    int tid = threadIdx.x;
    int loc[7]; int mysum = 0;
#pragma unroll
    for (int j = 0; j < 7; j++) {
        int b = tid * 7 + j;
        int h = (b < NB) ? hist[b] : 0;
        loc[j] = mysum; mysum += h;
    }
    scan[tid] = mysum;
    __syncthreads();
    int incl = mysum;
    for (int off = 1; off < 256; off <<= 1) {
        int add = (tid >= off) ? scan[tid - off] : 0;
        __syncthreads();
        incl += add; scan[tid] = incl;
        __syncthreads();
    }
    int excl = incl - mysum;
#pragma unroll
    for (int j = 0; j < 7; j++) {
        int b = tid * 7 + j;
        if (b < NB) {
            int v = excl + loc[j];
            base[b] = v;
            cursor[b * 8] = (unsigned int)v;   // 32B-padded cursors
        }
    }
    if (tid == 255) base[NB] = incl;
}

// ---------------- launch 4: scatter edges into bucket lists (8B packed) ---
// (r3/r4-proven). One block per 8192-edge chunk.
__global__ __launch_bounds__(256) void k_scatter(const int* __restrict__ rows,
                                                 const int* __restrict__ cols,
                                                 const float* __restrict__ vals,
                                                 unsigned int* __restrict__ cursor,
                                                 uint2* __restrict__ ed, int E) {
    __shared__ int lcount[NB];
    __shared__ int lbase[NB];
    int tid = threadIdx.x;
    int c0 = blockIdx.x * CH;
    int cend = min(c0 + CH, E);
    for (int b = tid; b < NB; b += 256) lcount[b] = 0;
    __syncthreads();
    for (int i = c0 + tid; i < cend; i += 256)
        atomicAdd(&lcount[rows[i] >> BSHIFT], 1);
    __syncthreads();
    for (int b = tid; b < NB; b += 256) {
        int c = lcount[b];
        lbase[b] = c ? (int)atomicAdd(&cursor[b * 8], (unsigned int)c) : 0;
        lcount[b] = 0;
    }
    __syncthreads();
    for (int i = c0 + tid; i < cend; i += 256) {
        int r = rows[i];
        int b = r >> BSHIFT;
        int rank = atomicAdd(&lcount[b], 1);
        int pos = lbase[b] + rank;
        ed[pos] = make_uint2(((unsigned int)cols[i] << BSHIFT) |
                                 (unsigned int)(r & (BROWS - 1)),
                             __float_as_uint(vals[i]));
    }
}

// ---------------- launch 5: gacc — 4 blocks per bucket, LDS f32 acc -------
// 32 streams/block x ~16 iters -> dependent-chain latency hidden
// (r3's single-block/bucket version serialized 256 iters -> 347us).
// Merge: 32 random atomic lines per block, 200K total ~= 10us at the
// 20G-lines/s atomic wall (vs 3.2M lines for the per-edge path).
__global__ __launch_bounds__(256) void k_gacc(const uint2* __restrict__ ed,
                                              const int* __restrict__ base,
                                              const unsigned int* __restrict__ tb,
                                              unsigned int* __restrict__ g2) {
    __shared__ float gs[BROWS * H1];   // 4 KB f32 bucket slice
    const int tid = threadIdx.x;
    const int bb = blockIdx.x >> 2;         // bucket
    const int j  = blockIdx.x & (GSPLIT - 1);
    for (int i = tid; i < BROWS * H1; i += 256) gs[i] = 0.f;
    __syncthreads();
    const int e0 = base[bb], e1 = base[bb + 1];
    const int len = e1 - e0;
    const int es = e0 + ((len * j) >> 2);
    const int ee = e0 + ((len * (j + 1)) >> 2);
    const int f2 = tid & 7, grp = tid >> 3;   // 32 streams of 8 lanes
    for (int i = es + grp; i < ee; i += 32) {
        uint2 e = ed[i];
        int c  = (int)(e.x >> BSHIFT);
        int r6 = (int)(e.x & (BROWS - 1));
        float v = __uint_as_float(e.y);
        unsigned int tv = tb[c * 8 + f2];
        atomicAdd(&gs[r6 * H1 + 2 * f2],     v * bf_lo(tv));
        atomicAdd(&gs[r6 * H1 + 2 * f2 + 1], v * bf_hi(tv));
    }
    __syncthreads();
    // merge partial into g2 (bf16 pk atomics; 16 lanes per 64B line)
    const int row0 = bb << BSHIFT;
    for (int idx = tid; idx < BROWS * 8; idx += 256) {
        int row = idx >> 3, fp = idx & 7;
        unsigned int pk = pack_bf16(gs[row * H1 + 2 * fp],
                                    gs[row * H1 + 2 * fp + 1]);
        unsigned int* addr = g2 + (size_t)(row0 + row) * 8 + fp;
        asm volatile("global_atomic_pk_add_bf16 %0, %1, off"
                     :: "v"(addr), "v"(pk) : "memory");
    }
}

// ---------------- launch 6: s[f]=sum_e val*relu(g[col]); last block: out --
__global__ __launch_bounds__(256) void k_s2out(const int* __restrict__ cols,
                                               const float* __restrict__ vals,
                                               const unsigned int* __restrict__ g2,
                                               float* __restrict__ s,
                                               unsigned int* __restrict__ flag,
                                               const float* __restrict__ W2,
                                               const float* __restrict__ w_out,
                                               const float* __restrict__ b_out,
                                               float* __restrict__ out, int E) {
    const int tid = threadIdx.x;
    const int f2 = tid & 7;
    int idx    = (blockIdx.x * 256 + tid) >> 3;
    int stride = (gridDim.x * 256) >> 3;
    float accl = 0.f, acch = 0.f;
    for (int e = idx; e < E; e += stride) {
        int c = cols[e];
        float v = vals[e];
        unsigned int gv = g2[c * 8 + f2];
        accl = fmaf(v, fmaxf(bf_lo(gv), 0.f), accl);
        acch = fmaf(v, fmaxf(bf_hi(gv), 0.f), acch);
    }
    accl += __shfl_xor(accl, 8, 64);
    accl += __shfl_xor(accl, 16, 64);
    accl += __shfl_xor(accl, 32, 64);
    acch += __shfl_xor(acch, 8, 64);
    acch += __shfl_xor(acch, 16, 64);
    acch += __shfl_xor(acch, 32, 64);
    __shared__ float red[4][16];
    __shared__ int slast;
    int lane = tid & 63, wid = tid >> 6;
    if (lane < 8) { red[wid][2 * lane] = accl; red[wid][2 * lane + 1] = acch; }
    __syncthreads();
    if (tid < 16) {
        float v = red[0][tid] + red[1][tid] + red[2][tid] + red[3][tid];
        atomicAdd(&s[tid], v);
    }
    if (tid == 0) {
        __threadfence();
        unsigned int old = atomicAdd(flag, 1u);
        slast = (old == gridDim.x - 1) ? 1 : 0;
    }
    __syncthreads();
    if (slast && tid < 64) {
        float sv = (tid < H1) ? atomicAdd(&s[tid], 0.f) : 0.f;
        float m = 0.f;
        if (tid < H2) {
            float v = 0.f;
#pragma unroll
            for (int f1 = 0; f1 < H1; f1++)
                v = fmaf(__shfl(sv, f1, 64), W2[f1 * H2 + tid], v);
            m = v * w_out[tid];
        }
        for (int off = 32; off; off >>= 1) m += __shfl_down(m, off, 64);
        if (tid == 0) out[0] = 1.f / (1.f + expf(-(m + b_out[0])));
    }
}

// ---------------- fallback edge pass (r6-proven, at the atomic wall) ------
__global__ __launch_bounds__(256) void k_edge(const int* __restrict__ rows,
                                              const int* __restrict__ cols,
                                              const float* __restrict__ vals,
                                              const unsigned int* __restrict__ tb,
                                              unsigned int* __restrict__ g2, int E) {
    int tid = blockIdx.x * 256 + threadIdx.x;
    int e = tid >> 3;
    int f2 = tid & 7;
    if (e >= E) return;
    int r = rows[e];
    int c = cols[e];
    float v = vals[e];
    unsigned int tv = tb[c * 8 + f2];
    unsigned int pk = pack_bf16(v * bf_lo(tv), v * bf_hi(tv));
    unsigned int* addr = g2 + (r * 8 + f2);
    asm volatile("global_atomic_pk_add_bf16 %0, %1, off"
                 :: "v"(addr), "v"(pk) : "memory");
}

extern "C" void kernel_launch(void* const* d_in, const int* in_sizes, int n_in,
                              void* d_out, int out_size, void* d_ws, size_t ws_size,
                              hipStream_t stream) {
    const float* x         = (const float*)d_in[0];
    const float* edge_vals = (const float*)d_in[1];
    const float* W1        = (const float*)d_in[2];
    const float* W2        = (const float*)d_in[3];
    const float* w_out     = (const float*)d_in[4];
    const float* b_out     = (const float*)d_in[5];
    const int*   edge_rows = (const int*)d_in[6];
    const int*   edge_cols = (const int*)d_in[7];
    float* out = (float*)d_out;

    const int E = in_sizes[1];   // 3.2M

    // workspace layout (bytes, 64B-aligned):
    //   t      (bf16): [0,         3,200,000)
    //   g2     (bf16): [3,200,000, 6,401,024)   NB*64 rows * 32B  (zeroed)
    //   s      (fp32): [6,401,024, 6,401,088)   (zeroed)
    //   flag   (u32):  [6,401,088, 6,401,152)   (zeroed)
    //   hist   (int):  [6,401,152, 6,407,424)   NB ints + pad     (zeroed)
    //   base   (int):  [6,407,424, 6,413,696)   NB+1 ints + pad
    //   cursor (u32):  [6,413,696, 6,463,744)   NB * 32B
    //   ed     (8B):   [6,463,744, 32,063,744)  E * 8B
    char* ws = (char*)d_ws;
    unsigned short* t    = (unsigned short*)(ws);
    unsigned int*   g2   = (unsigned int*)(ws + 3200000);
    float*          s    = (float*)(ws + 6401024);
    unsigned int*   flag = (unsigned int*)(ws + 6401088);
    int*            hist = (int*)(ws + 6401152);
    int*            base = (int*)(ws + 6407424);
    unsigned int*   cur  = (unsigned int*)(ws + 6413696);
    uint2*          ed   = (uint2*)(ws + 6463744);

    // launch 1: xw1 + zero g2/s/flag/hist
    k_xw1z<<<NT1, 256, 0, stream>>>(x, W1, t, (float4*)(ws + 3200000));

    bool binned = (ws_size >= 32063744) && (E <= 3200000);
    if (binned) {
        k_hist<<<256, 256, 0, stream>>>(edge_rows, hist, E);
        k_scan<<<1, 256, 0, stream>>>(hist, base, cur);
        k_scatter<<<(E + CH - 1) / CH, 256, 0, stream>>>(
            edge_rows, edge_cols, edge_vals, cur, ed, E);
        k_gacc<<<NB * GSPLIT, 256, 0, stream>>>(ed, base,
                                                (const unsigned int*)t, g2);
    } else {
        long long edge_threads = (long long)E * 8;
        k_edge<<<(int)((edge_threads + 255) / 256), 256, 0, stream>>>(
            edge_rows, edge_cols, edge_vals, (const unsigned int*)t, g2, E);
    }

    k_s2out<<<1024, 256, 0, stream>>>(edge_cols, edge_vals, g2, s, flag,
                                      W2, w_out, b_out, out, E);
}

// Round 9
// 413.914 us; speedup vs baseline: 1.5718x; 1.5718x over previous
//
#include <hip/hip_runtime.h>
#include <math.h>

#define N_NODES 100000
#define D_IN 256
#define H1 16
#define H2 32
#define NT1 1563                 // ceil(N_NODES / 64): one 16-row tile per wave

// ---------- bf16 helpers (manual, RNE) ----------
static __device__ __forceinline__ float bf_lo(unsigned int u) {
    return __uint_as_float(u << 16);
}
static __device__ __forceinline__ float bf_hi(unsigned int u) {
    return __uint_as_float(u & 0xffff0000u);
}
static __device__ __forceinline__ unsigned int f2bf_rne(float f) {
    unsigned int u = __float_as_uint(f);
    return (u + 0x7fffu + ((u >> 16) & 1u)) >> 16;
}
static __device__ __forceinline__ unsigned int pack_bf16(float lo, float hi) {
    return f2bf_rne(lo) | (f2bf_rne(hi) << 16);
}
static __device__ __forceinline__ unsigned int cvt_pk_bf16(float lo, float hi) {
    unsigned int r;
    asm("v_cvt_pk_bf16_f32 %0, %1, %2" : "=v"(r) : "v"(lo), "v"(hi));
    return r;
}

typedef __attribute__((ext_vector_type(8))) short bf16x8;
typedef __attribute__((ext_vector_type(4))) float f32x4;
union ABFrag { unsigned int u[4]; bf16x8 v; };

// ---------------- launch 1: t = bf16(x@W1), fused zero of g2/s/flag -------
// One MFMA 16x16x32 tile (16 rows) per wave; 4 waves/block -> 64 rows/block,
// 1563 blocks. Layouts (r2-proven, absmax 0): A: row=l&15, k=(l>>4)*8+e;
// B: col=l&15 same k; D: col=l&15, row=(l>>4)*4+reg.
__global__ __launch_bounds__(256) void k_xw1z(const float* __restrict__ x,
                                              const float* __restrict__ W1,
                                              unsigned short* __restrict__ t,
                                              float4* __restrict__ g2z,
                                              float* __restrict__ s,
                                              unsigned int* __restrict__ flag) {
    const int tid = threadIdx.x;
    const int bid = blockIdx.x;

    // fused zeroing: g2 = 200,000 float4 over 1563*256 = 400,128 threads
    int zi = bid * 256 + tid;
    if (zi < 200000) g2z[zi] = make_float4(0.f, 0.f, 0.f, 0.f);
    if (bid == 0) {
        if (tid < 16) s[tid] = 0.f;
        if (tid == 16) *flag = 0u;
    }

    const int lane = tid & 63;
    const int wid  = tid >> 6;
    const int fcol = lane & 15;
    const int kgrp = lane >> 4;

    // B-frags: bfrag[g] covers W1[32g .. 32g+31][0..15] (L2-broadcast loads)
    ABFrag bfrag[8];
#pragma unroll
    for (int g = 0; g < 8; g++) {
        const float* wp = W1 + (g * 32 + kgrp * 8) * H1 + fcol;
#pragma unroll
        for (int p = 0; p < 4; p++)
            bfrag[g].u[p] = cvt_pk_bf16(wp[(2 * p) * H1], wp[(2 * p + 1) * H1]);
    }

    const int row0 = bid * 64 + wid * 16;
    int arow = row0 + fcol;
    if (arow >= N_NODES) arow = N_NODES - 1;   // clamp for safe loads
    const float* xr = x + (size_t)arow * D_IN;
    f32x4 acc = {0.f, 0.f, 0.f, 0.f};
#pragma unroll
    for (int g = 0; g < 8; g++) {
        const float4 a0 = *(const float4*)(xr + g * 32 + kgrp * 8);
        const float4 a1 = *(const float4*)(xr + g * 32 + kgrp * 8 + 4);
        ABFrag af;
        af.u[0] = cvt_pk_bf16(a0.x, a0.y);
        af.u[1] = cvt_pk_bf16(a0.z, a0.w);
        af.u[2] = cvt_pk_bf16(a1.x, a1.y);
        af.u[3] = cvt_pk_bf16(a1.z, a1.w);
        acc = __builtin_amdgcn_mfma_f32_16x16x32_bf16(af.v, bfrag[g].v, acc, 0, 0, 0);
    }
#pragma unroll
    for (int r = 0; r < 4; r++) {
        int orow = row0 + kgrp * 4 + r;
        if (orow < N_NODES)
            t[(size_t)orow * H1 + fcol] = (unsigned short)f2bf_rne(acc[r]);
    }
}

// ---------------- launch 2: g[r] += val * t[c] (at the atomic wall) -------
// 8 lanes/edge, one pk-bf16 atomic per lane -> exactly one random atomic
// line-transaction per edge; measured wall = 20G line-transactions/s
// (invariant across r0/r1/r2: bytes, op count, occupancy all varied, the
// line count alone predicted time). Pre-aggregation alternatives measured
// worse: binned r3/r8 (LDS-atomic wall ~0.7 lane-ops/cy/CU + ~130us
// reorganization passes), cooperative fusion r4 (grid.sync ~100s of us).
__global__ __launch_bounds__(256) void k_edge(const int* __restrict__ rows,
                                              const int* __restrict__ cols,
                                              const float* __restrict__ vals,
                                              const unsigned int* __restrict__ tb,
                                              unsigned int* __restrict__ g2, int E) {
    int tid = blockIdx.x * 256 + threadIdx.x;
    int e = tid >> 3;
    int f2 = tid & 7;
    if (e >= E) return;
    int r = rows[e];
    int c = cols[e];
    float v = vals[e];
    unsigned int tv = tb[c * 8 + f2];
    unsigned int pk = pack_bf16(v * bf_lo(tv), v * bf_hi(tv));
    unsigned int* addr = g2 + (r * 8 + f2);
    asm volatile("global_atomic_pk_add_bf16 %0, %1, off"
                 :: "v"(addr), "v"(pk) : "memory");
}

// ---------------- launch 3: s[f]=sum_e val*relu(g[col]); last block: out ---
__global__ __launch_bounds__(256) void k_s2out(const int* __restrict__ cols,
                                               const float* __restrict__ vals,
                                               const unsigned int* __restrict__ g2,
                                               float* __restrict__ s,
                                               unsigned int* __restrict__ flag,
                                               const float* __restrict__ W2,
                                               const float* __restrict__ w_out,
                                               const float* __restrict__ b_out,
                                               float* __restrict__ out, int E) {
    const int tid = threadIdx.x;
    const int f2 = tid & 7;
    int idx    = (blockIdx.x * 256 + tid) >> 3;
    int stride = (gridDim.x * 256) >> 3;
    float accl = 0.f, acch = 0.f;
    for (int e = idx; e < E; e += stride) {
        int c = cols[e];
        float v = vals[e];
        unsigned int gv = g2[c * 8 + f2];
        accl = fmaf(v, fmaxf(bf_lo(gv), 0.f), accl);
        acch = fmaf(v, fmaxf(bf_hi(gv), 0.f), acch);
    }
    accl += __shfl_xor(accl, 8, 64);
    accl += __shfl_xor(accl, 16, 64);
    accl += __shfl_xor(accl, 32, 64);
    acch += __shfl_xor(acch, 8, 64);
    acch += __shfl_xor(acch, 16, 64);
    acch += __shfl_xor(acch, 32, 64);
    __shared__ float red[4][16];
    __shared__ int slast;
    int lane = tid & 63, wid = tid >> 6;
    if (lane < 8) { red[wid][2 * lane] = accl; red[wid][2 * lane + 1] = acch; }
    __syncthreads();
    if (tid < 16) {
        float v = red[0][tid] + red[1][tid] + red[2][tid] + red[3][tid];
        atomicAdd(&s[tid], v);
    }
    // ---- last-block-done detection, then fused k_out ----
    if (tid == 0) {
        __threadfence();                          // make s-adds visible
        unsigned int old = atomicAdd(flag, 1u);
        slast = (old == gridDim.x - 1) ? 1 : 0;
    }
    __syncthreads();
    if (slast && tid < 64) {
        // coherent read of s via atomic RMW (bypasses stale local caches)
        float sv = (tid < H1) ? atomicAdd(&s[tid], 0.f) : 0.f;
        float m = 0.f;
        if (tid < H2) {
            float v = 0.f;
#pragma unroll
            for (int f1 = 0; f1 < H1; f1++)
                v = fmaf(__shfl(sv, f1, 64), W2[f1 * H2 + tid], v);
            m = v * w_out[tid];
        }
        for (int off = 32; off; off >>= 1) m += __shfl_down(m, off, 64);
        if (tid == 0) out[0] = 1.f / (1.f + expf(-(m + b_out[0])));
    }
}

extern "C" void kernel_launch(void* const* d_in, const int* in_sizes, int n_in,
                              void* d_out, int out_size, void* d_ws, size_t ws_size,
                              hipStream_t stream) {
    const float* x         = (const float*)d_in[0];
    const float* edge_vals = (const float*)d_in[1];
    const float* W1        = (const float*)d_in[2];
    const float* W2        = (const float*)d_in[3];
    const float* w_out     = (const float*)d_in[4];
    const float* b_out     = (const float*)d_in[5];
    const int*   edge_rows = (const int*)d_in[6];
    const int*   edge_cols = (const int*)d_in[7];
    float* out = (float*)d_out;

    const int E = in_sizes[1];   // 3.2M

    // workspace layout (bytes):
    //   t   (bf16): [0,         3,200,000)
    //   g2  (bf16): [3,200,000, 6,400,000)   zeroed in k_xw1z
    //   s   (fp32): [6,400,000, 6,400,064)   zeroed in k_xw1z
    //   flag(u32):  [6,400,128, 6,400,132)   zeroed in k_xw1z
    char* ws = (char*)d_ws;
    unsigned short* t    = (unsigned short*)(ws);
    unsigned int*   g2   = (unsigned int*)(ws + 3200000);
    float*          s    = (float*)(ws + 6400000);
    unsigned int*   flag = (unsigned int*)(ws + 6400128);

    k_xw1z<<<NT1, 256, 0, stream>>>(x, W1, t, (float4*)g2, s, flag);

    long long edge_threads = (long long)E * 8;
    k_edge<<<(int)((edge_threads + 255) / 256), 256, 0, stream>>>(
        edge_rows, edge_cols, edge_vals, (const unsigned int*)t, g2, E);

    k_s2out<<<1024, 256, 0, stream>>>(edge_cols, edge_vals, g2, s, flag,
                                      W2, w_out, b_out, out, E);
}